// Round 5
// baseline (56.143 us; speedup 1.0000x reference)
//
#include <hip/hip_runtime.h>
#include <hip/hip_bf16.h>
#include <math.h>

typedef __attribute__((ext_vector_type(8))) short short8;
typedef __attribute__((ext_vector_type(4))) float f32x4;
typedef unsigned int u32;
typedef unsigned long long u64;

// 20-byte feature element: d[0..3] = 8 spline bf16 slots, d[4] = gelu|pad
struct FeatElem { u32 d[5]; };

// ---------------------------------------------------------------------------
// Weight pack: layer_weight (32,144,3,3) f32 -> bf16 B-fragments.
// K-order: k<128 -> spline (icg*8+jj) [= lw's channel order], 128..143 ->
// base/gelu (icg), 144..159 zero. Page = (tap*5+ks)*2+nt.
// B-frag (16x16x32): col(oc) = lane&15, k = ks*32 + (lane>>4)*8 + e.
// ---------------------------------------------------------------------------
__global__ void wtrans(const float* __restrict__ lw, ushort* __restrict__ w2) {
    int t = blockIdx.x * 256 + threadIdx.x;
    if (t >= 5760) return;
    int l    = t & 63;
    int page = t >> 6;
    int nt  = page & 1;
    int ks  = (page >> 1) % 5;
    int tap = page / 10;
    int oc = nt * 16 + (l & 15);
    int kbase = ks * 32 + (l >> 4) * 8;
    short8 v;
#pragma unroll
    for (int e = 0; e < 8; ++e) {
        int k = kbase + e;
        float val = (k < 144) ? lw[(oc * 144 + k) * 9 + tap] : 0.f;
        __hip_bfloat16 hb = __float2bfloat16(val);
        v[e] = *(short*)&hb;
    }
    ((short8*)w2)[t] = v;
}

// ---------------------------------------------------------------------------
// Feature expansion: each of 512 channels gets a zero-padded 66x66 plane of
// 20B elements (8 spline bf16 slots + gelu). Each element computed ONCE.
// Grid: (18, 512); t in [0,4608) covers 4356 = 66*66 padded positions.
// ---------------------------------------------------------------------------
__global__ __launch_bounds__(256) void featk(const float* __restrict__ x,
                                             ushort* __restrict__ FG) {
    int t = blockIdx.x * 256 + threadIdx.x;
    if (t >= 4356) return;
    int c  = blockIdx.y;
    int hp = t / 66, wp = t - hp * 66;      // padded coords
    bool img = (hp >= 1) && (hp <= 64) && (wp >= 1) && (wp <= 64);
    float xv = img ? x[(size_t)c * 4096 + (hp - 1) * 64 + (wp - 1)] : 0.f;

    // uniform cubic B-spline closed form; knots -2.2 + 0.4*i
    float tpos = (xv + 2.2f) * 2.5f;
    float cf = floorf(tpos);
    int ci = (int)cf;
    float u = tpos - cf;
    float u2 = u * u, u3 = u2 * u, om = 1.f - u;
    const float s6 = 1.f / 6.f;
    float q0 = om * om * om * s6;
    float q1 = (4.f - 6.f * u2 + 3.f * u3) * s6;
    float q2 = (1.f + 3.f * u + 3.f * u2 - 3.f * u3) * s6;
    float q3 = u3 * s6;
    __hip_bfloat16 hq0 = __float2bfloat16(q0);
    __hip_bfloat16 hq1 = __float2bfloat16(q1);
    __hip_bfloat16 hq2 = __float2bfloat16(q2);
    __hip_bfloat16 hq3 = __float2bfloat16(q3);
    u64 Q =   (u64)*(ushort*)&hq0
            | ((u64)*(ushort*)&hq1 << 16)
            | ((u64)*(ushort*)&hq2 << 32)
            | ((u64)*(ushort*)&hq3 << 48);
    u64 lo = 0, hi = 0;
    if (img && ci >= 0 && ci <= 10) {
        int s = ci * 16 - 48;
        if (s < 0)        { lo = Q >> (-s); }
        else if (s < 64)  { lo = Q << s; hi = s ? (Q >> (64 - s)) : 0ull; }
        else              { hi = Q << (s - 64); }
    }
    // gelu via branch-free poly erf (A&S 7.1.26)
    float z  = xv * 0.70710678118654752f;
    float az = fabsf(z);
    float tt = 1.f / fmaf(0.3275911f, az, 1.f);
    float poly = tt * fmaf(tt, fmaf(tt, fmaf(tt, fmaf(tt, 1.061405429f,
                  -1.453152027f), 1.421413741f), -0.284496736f),
                  0.254829592f);
    float er = 1.f - poly * __expf(-z * z);
    er = (z < 0.f) ? -er : er;
    float ge = img ? 0.5f * xv * (1.f + er) : 0.f;
    __hip_bfloat16 hg = __float2bfloat16(ge);

    FeatElem fe;
    fe.d[0] = (u32)(lo & 0xffffffffull);
    fe.d[1] = (u32)(lo >> 32);
    fe.d[2] = (u32)(hi & 0xffffffffull);
    fe.d[3] = (u32)(hi >> 32);
    fe.d[4] = (u32)*(ushort*)&hg;
    *(FeatElem*)(FG + ((size_t)c * 4356 + t) * 10) = fe;
}

// ---------------------------------------------------------------------------
// MFMA implicit-GEMM KAN conv. Block = (b, g, 4x16 tile). Halo 6x18 = 108 px.
// Staging = pure copy from padded feature array: per (icg,py) strip 18 elems,
// 2 threads x 9 elems; per elem: 20B global read -> ds_b128 + ds_b16.
// LDS row stride 168 ushort (336B = 84 dw = 20 mod 32 -> conflict-free b128).
// 4 waves = {ntile} x {tap-half}; 4 m-tiles each; partials combined via LDS.
// ---------------------------------------------------------------------------
__global__ __launch_bounds__(256) void kanconv(const ushort* __restrict__ FG,
                                               const ushort* __restrict__ w2,
                                               float* __restrict__ y) {
    __shared__ __align__(16) ushort Fs[108 * 168];
    const int tid  = threadIdx.x;
    const int tile = blockIdx.x;          // 0..63 : 16 row-tiles x 4 col-tiles
    const int b    = blockIdx.y;
    const int g    = blockIdx.z;
    const int h0 = (tile >> 2) * 4;
    const int w0 = (tile & 3) * 16;

    // ---- stage: copy features (96 strips x 18 elems) ----
    if (tid < 192) {
        int st = tid >> 1, half = tid & 1;
        int icg = st / 6, py = st - icg * 6;
        const ushort* gp = FG + (((size_t)(b * 64 + g * 16 + icg) * 66
                                  + (h0 + py)) * 66 + (w0 + 9 * half)) * 10;
        ushort* lp = &Fs[(py * 18 + 9 * half) * 168 + icg * 8];
        ushort* lg = &Fs[(py * 18 + 9 * half) * 168 + 128 + icg];
#pragma unroll
        for (int j = 0; j < 9; ++j) {
            FeatElem fe = *(const FeatElem*)(gp + (size_t)j * 10);
            uint4 sv; sv.x = fe.d[0]; sv.y = fe.d[1]; sv.z = fe.d[2]; sv.w = fe.d[3];
            *(uint4*)(lp + j * 168) = sv;
            lg[j * 168] = (ushort)fe.d[4];
        }
    }
    // zero pad k in [144,160)
    {
        short8 z8 = {0, 0, 0, 0, 0, 0, 0, 0};
        for (int e = tid; e < 216; e += 256) {
            int p = e >> 1;
            *(short8*)&Fs[p * 168 + 144 + (e & 1) * 8] = z8;
        }
    }
    __syncthreads();

    const int wv = tid >> 6;
    const int l  = tid & 63;
    const int lx = l & 15, q = l >> 4;
    const int nt    = wv >> 1;            // 0,1 : oc tile
    const int khalf = wv & 1;             // 0: taps 0..4, 1: taps 5..8
    const int tap_lo = khalf ? 5 : 0;
    const int tap_hi = khalf ? 9 : 5;

    f32x4 acc0 = {0.f, 0.f, 0.f, 0.f};
    f32x4 acc1 = acc0, acc2 = acc0, acc3 = acc0;
    const short8* w8 = (const short8*)w2;
    const int lane_off = lx * 168 + q * 8;

#pragma unroll 1
    for (int tap = tap_lo; tap < tap_hi; ++tap) {
        const int kh = tap / 3, kw = tap - kh * 3;
        const ushort* arow = &Fs[(kh * 18 + kw) * 168 + lane_off];
        const short8* bp = w8 + (tap * 10 + nt) * 64 + l;
#pragma unroll
        for (int ks = 0; ks < 5; ++ks) {
            short8 bf = bp[ks * 128];
            short8 a0 = *(const short8*)(arow + 0 * 3024 + ks * 32);
            short8 a1 = *(const short8*)(arow + 1 * 3024 + ks * 32);
            short8 a2 = *(const short8*)(arow + 2 * 3024 + ks * 32);
            short8 a3 = *(const short8*)(arow + 3 * 3024 + ks * 32);
            acc0 = __builtin_amdgcn_mfma_f32_16x16x32_bf16(a0, bf, acc0, 0, 0, 0);
            acc1 = __builtin_amdgcn_mfma_f32_16x16x32_bf16(a1, bf, acc1, 0, 0, 0);
            acc2 = __builtin_amdgcn_mfma_f32_16x16x32_bf16(a2, bf, acc2, 0, 0, 0);
            acc3 = __builtin_amdgcn_mfma_f32_16x16x32_bf16(a3, bf, acc3, 0, 0, 0);
        }
    }

    // ---- combine tap-halves through LDS (stride 20 dw) ----
    __syncthreads();
    float* comb = (float*)Fs;
    if (khalf == 1) {
        float* cp = comb + (nt * 64 + l) * 20;
        *(f32x4*)(cp + 0)  = acc0;
        *(f32x4*)(cp + 4)  = acc1;
        *(f32x4*)(cp + 8)  = acc2;
        *(f32x4*)(cp + 12) = acc3;
    }
    __syncthreads();
    if (khalf == 0) {
        const float* cp = comb + (nt * 64 + l) * 20;
        f32x4 o0 = acc0 + *(const f32x4*)(cp + 0);
        f32x4 o1 = acc1 + *(const f32x4*)(cp + 4);
        f32x4 o2 = acc2 + *(const f32x4*)(cp + 8);
        f32x4 o3 = acc3 + *(const f32x4*)(cp + 12);
        // D layout: col(oc-in-tile) = lx, px = q*4 + reg; rows = m-tile 0..3
        float* yb = y + ((size_t)b * 128 + g * 32 + nt * 16 + lx) * 4096
                      + h0 * 64 + w0 + q * 4;
        *(f32x4*)(yb + 0 * 64) = o0;
        *(f32x4*)(yb + 1 * 64) = o1;
        *(f32x4*)(yb + 2 * 64) = o2;
        *(f32x4*)(yb + 3 * 64) = o3;
    }
}

// ---------------------------------------------------------------------------
// Fused instance-norm + PReLU: one block per (b,c); 16 floats/thread in regs.
// ---------------------------------------------------------------------------
__global__ __launch_bounds__(256) void instnorm(float* __restrict__ y,
                                                const float* __restrict__ prelu) {
    const int blk = blockIdx.x;  // b*128 + c
    const int tid = threadIdx.x;
    float4* yp = (float4*)(y + (size_t)blk * 4096);
    float4 v0 = yp[tid], v1 = yp[tid + 256], v2 = yp[tid + 512], v3 = yp[tid + 768];
    float s  = v0.x + v0.y + v0.z + v0.w + v1.x + v1.y + v1.z + v1.w
             + v2.x + v2.y + v2.z + v2.w + v3.x + v3.y + v3.z + v3.w;
    float s2 = v0.x*v0.x + v0.y*v0.y + v0.z*v0.z + v0.w*v0.w
             + v1.x*v1.x + v1.y*v1.y + v1.z*v1.z + v1.w*v1.w
             + v2.x*v2.x + v2.y*v2.y + v2.z*v2.z + v2.w*v2.w
             + v3.x*v3.x + v3.y*v3.y + v3.z*v3.z + v3.w*v3.w;
#pragma unroll
    for (int off = 32; off > 0; off >>= 1) {
        s  += __shfl_down(s, off);
        s2 += __shfl_down(s2, off);
    }
    __shared__ float red[8];
    int wave = tid >> 6;
    if ((tid & 63) == 0) { red[wave] = s; red[4 + wave] = s2; }
    __syncthreads();
    float S  = red[0] + red[1] + red[2] + red[3];
    float S2 = red[4] + red[5] + red[6] + red[7];
    float mean = S * (1.0f / 4096.0f);
    float var  = S2 * (1.0f / 4096.0f) - mean * mean;
    float rstd = rsqrtf(var + 1e-5f);
    float slope = prelu[(blk >> 5) & 3];
    float t;
    float4 o;
#define NRM(vv)                                                               \
    t = (vv.x - mean) * rstd; o.x = t >= 0.f ? t : slope * t;                 \
    t = (vv.y - mean) * rstd; o.y = t >= 0.f ? t : slope * t;                 \
    t = (vv.z - mean) * rstd; o.z = t >= 0.f ? t : slope * t;                 \
    t = (vv.w - mean) * rstd; o.w = t >= 0.f ? t : slope * t;
    NRM(v0); yp[tid]       = o;
    NRM(v1); yp[tid + 256] = o;
    NRM(v2); yp[tid + 512] = o;
    NRM(v3); yp[tid + 768] = o;
#undef NRM
}

extern "C" void kernel_launch(void* const* d_in, const int* in_sizes, int n_in,
                              void* d_out, int out_size, void* d_ws, size_t ws_size,
                              hipStream_t stream) {
    const float* x     = (const float*)d_in[0];
    const float* lw    = (const float*)d_in[1];
    const float* prelu = (const float*)d_in[2];
    float*  out = (float*)d_out;
    ushort* w2  = (ushort*)d_ws;                        // 92160 B
    ushort* FG  = (ushort*)((char*)d_ws + 92160);       // 512*66*66*20 B

    wtrans<<<23, 256, 0, stream>>>(lw, w2);
    dim3 fgrid(18, 512);
    featk<<<fgrid, 256, 0, stream>>>(x, FG);
    dim3 grid(64, 8, 4);
    kanconv<<<grid, 256, 0, stream>>>(FG, w2, out);
    instnorm<<<1024, 256, 0, stream>>>(out, prelu);
}

// Round 6
// 42.684 us; speedup vs baseline: 1.3153x; 1.3153x over previous
//
#include <hip/hip_runtime.h>
#include <hip/hip_bf16.h>
#include <math.h>

typedef __attribute__((ext_vector_type(8))) short short8;
typedef __attribute__((ext_vector_type(4))) float f32x4;
typedef __attribute__((ext_vector_type(16))) float f32x16;
typedef unsigned int u32;
typedef unsigned long long u64;

// ---------------------------------------------------------------------------
// Weight pack: layer_weight (32,144,3,3) f32 -> bf16 A-fragments for
// mfma_f32_32x32x16_bf16 (weights are the A operand, M=32=oc, K=144).
// Page = tap*9 + ks (81 pages x 64 lanes x 8 bf16).
// A-frag: row(oc) = lane&31, k = ks*16 + (lane>>5)*8 + e.
// k-order: k<128 -> spline (icg*8+jj) [= lw channel order], 128..143 -> gelu.
// ---------------------------------------------------------------------------
__global__ void wtrans(const float* __restrict__ lw, ushort* __restrict__ w2) {
    int t = blockIdx.x * 256 + threadIdx.x;
    if (t >= 5184) return;
    int l    = t & 63;
    int page = t >> 6;          // 0..80
    int ks  = page % 9;
    int tap = page / 9;
    int oc = l & 31;
    int kbase = ks * 16 + ((l >> 5) << 3);
    short8 v;
#pragma unroll
    for (int e = 0; e < 8; ++e) {
        int k = kbase + e;      // < 144 always
        float val = lw[(oc * 144 + k) * 9 + tap];
        __hip_bfloat16 hb = __float2bfloat16(val);
        v[e] = *(short*)&hb;
    }
    ((short8*)w2)[t] = v;
}

// ---------------------------------------------------------------------------
// MFMA implicit-GEMM KAN conv, 32x32x16 bf16, K=144 (no pad).
// Block = (b, g, 4x16 tile). Halo 6x18 = 108 px, row stride 152 ushort
// (304B = 19 x 16B slots, odd -> conflict-free b128).
// 4 waves = {pixel-half pt} x {tap-half khalf}. Weights = A (oc rows),
// features = B (pixel cols). khalf partials combined via LDS.
// ---------------------------------------------------------------------------
__global__ __launch_bounds__(256) void kanconv(const float* __restrict__ x,
                                               const ushort* __restrict__ w2,
                                               float* __restrict__ y) {
    __shared__ __align__(16) ushort Fs[108 * 152];   // 32,832 B
    const int tid  = threadIdx.x;
    const int tile = blockIdx.x;          // 0..63 : 16 row-tiles x 4 col-tiles
    const int b    = blockIdx.y;
    const int g    = blockIdx.z;
    const int h0 = (tile >> 2) * 4;
    const int w0 = (tile & 3) * 16;
    const float* xg = x + ((size_t)(b * 64 + g * 16)) * 4096;

    // ---- stage features (halo 6x18 = 108 px, 16 icg), computed in-place ----
#pragma unroll 1
    for (int it = 0; it < 7; ++it) {
        int e = it * 256 + tid;
        if (e < 1728) {
            int icg = e / 108;
            int p   = e - icg * 108;
            int py = p / 18, px = p - py * 18;
            int hy = h0 + py - 1, wx = w0 + px - 1;
            bool img = ((unsigned)hy < 64u) && ((unsigned)wx < 64u);
            float xv = img ? xg[icg * 4096 + hy * 64 + wx] : 0.f;
            // uniform cubic B-spline closed form; knots -2.2 + 0.4*i
            float tpos = (xv + 2.2f) * 2.5f;
            float cf = floorf(tpos);
            int ci = (int)cf;
            float u = tpos - cf;
            float u2 = u * u, u3 = u2 * u, om = 1.f - u;
            const float s6 = 1.f / 6.f;
            float q0 = om * om * om * s6;
            float q1 = (4.f - 6.f * u2 + 3.f * u3) * s6;
            float q2 = (1.f + 3.f * u + 3.f * u2 - 3.f * u3) * s6;
            float q3 = u3 * s6;
            __hip_bfloat16 hq0 = __float2bfloat16(q0);
            __hip_bfloat16 hq1 = __float2bfloat16(q1);
            __hip_bfloat16 hq2 = __float2bfloat16(q2);
            __hip_bfloat16 hq3 = __float2bfloat16(q3);
            u64 Q =   (u64)*(ushort*)&hq0
                    | ((u64)*(ushort*)&hq1 << 16)
                    | ((u64)*(ushort*)&hq2 << 32)
                    | ((u64)*(ushort*)&hq3 << 48);
            u64 lo = 0, hi = 0;
            if (img && ci >= 0 && ci <= 10) {
                int s = ci * 16 - 48;
                if (s < 0)        { lo = Q >> (-s); }
                else if (s < 64)  { lo = Q << s; hi = s ? (Q >> (64 - s)) : 0ull; }
                else              { hi = Q << (s - 64); }
            }
            union { u64 u64v[2]; short8 s8; } un;
            un.u64v[0] = lo; un.u64v[1] = hi;
            ushort* row = &Fs[p * 152];
            *(short8*)(row + icg * 8) = un.s8;
            // gelu via branch-free poly erf (A&S 7.1.26)
            float z  = xv * 0.70710678118654752f;
            float az = fabsf(z);
            float tt = 1.f / fmaf(0.3275911f, az, 1.f);
            float poly = tt * fmaf(tt, fmaf(tt, fmaf(tt, fmaf(tt, 1.061405429f,
                          -1.453152027f), 1.421413741f), -0.284496736f),
                          0.254829592f);
            float er = 1.f - poly * __expf(-z * z);
            er = (z < 0.f) ? -er : er;
            float ge = 0.5f * xv * (1.f + er);
            __hip_bfloat16 hg = __float2bfloat16(ge);
            row[128 + icg] = *(ushort*)&hg;
        }
    }
    __syncthreads();

    const int wv = tid >> 6;
    const int l  = tid & 63;
    const int khalf = wv & 1;             // 0: taps 0..4, 1: taps 5..8
    const int pt    = wv >> 1;            // pixel half (N-tile)
    const int pix  = pt * 32 + (l & 31);
    const int prow = pix >> 4, pcol = pix & 15;
    const int klo  = l >> 5;              // k sub-half

    f32x16 acc;
#pragma unroll
    for (int i = 0; i < 16; ++i) acc[i] = 0.f;
    const short8* w8 = (const short8*)w2;
    const int tap_lo = khalf ? 5 : 0;
    const int tap_hi = khalf ? 9 : 5;

#pragma unroll 1
    for (int tap = tap_lo; tap < tap_hi; ++tap) {
        const int kh = tap / 3, kw = tap - kh * 3;
        const ushort* fb = &Fs[((prow + kh) * 18 + (pcol + kw)) * 152 + klo * 8];
        const short8* ap = w8 + tap * 576 + l;
#pragma unroll
        for (int ks = 0; ks < 9; ++ks) {
            short8 a  = ap[ks * 64];                         // weights (A)
            short8 bf = *(const short8*)(fb + ks * 16);      // features (B)
            acc = __builtin_amdgcn_mfma_f32_32x32x16_bf16(a, bf, acc, 0, 0, 0);
        }
    }

    // ---- combine tap-halves through LDS (stride 20 floats) ----
    __syncthreads();                      // all feature reads done
    float* comb = (float*)Fs;             // [pt][lane] stride 20
    if (khalf == 1) {
        float* cp = comb + (pt * 64 + l) * 20;
        *(f32x4*)(cp + 0)  = f32x4{acc[0], acc[1], acc[2], acc[3]};
        *(f32x4*)(cp + 4)  = f32x4{acc[4], acc[5], acc[6], acc[7]};
        *(f32x4*)(cp + 8)  = f32x4{acc[8], acc[9], acc[10], acc[11]};
        *(f32x4*)(cp + 12) = f32x4{acc[12], acc[13], acc[14], acc[15]};
    }
    __syncthreads();
    if (khalf == 0) {
        const float* cp = comb + (pt * 64 + l) * 20;
        // D: col(pixel) = lane&31, row(oc) = (r&3) + 8*(r>>2) + 4*klo
        float* yb = y + (((size_t)b * 128 + g * 32) * 64 + h0 + prow) * 64
                      + w0 + pcol;
#pragma unroll
        for (int r = 0; r < 16; ++r) {
            int oc = (r & 3) + 8 * (r >> 2) + 4 * klo;
            yb[(size_t)oc * 4096] = acc[r] + cp[r];
        }
    }
}

// ---------------------------------------------------------------------------
// Fused instance-norm + PReLU: one block per (b,c); 16 floats/thread in regs.
// ---------------------------------------------------------------------------
__global__ __launch_bounds__(256) void instnorm(float* __restrict__ y,
                                                const float* __restrict__ prelu) {
    const int blk = blockIdx.x;  // b*128 + c
    const int tid = threadIdx.x;
    float4* yp = (float4*)(y + (size_t)blk * 4096);
    float4 v0 = yp[tid], v1 = yp[tid + 256], v2 = yp[tid + 512], v3 = yp[tid + 768];
    float s  = v0.x + v0.y + v0.z + v0.w + v1.x + v1.y + v1.z + v1.w
             + v2.x + v2.y + v2.z + v2.w + v3.x + v3.y + v3.z + v3.w;
    float s2 = v0.x*v0.x + v0.y*v0.y + v0.z*v0.z + v0.w*v0.w
             + v1.x*v1.x + v1.y*v1.y + v1.z*v1.z + v1.w*v1.w
             + v2.x*v2.x + v2.y*v2.y + v2.z*v2.z + v2.w*v2.w
             + v3.x*v3.x + v3.y*v3.y + v3.z*v3.z + v3.w*v3.w;
#pragma unroll
    for (int off = 32; off > 0; off >>= 1) {
        s  += __shfl_down(s, off);
        s2 += __shfl_down(s2, off);
    }
    __shared__ float red[8];
    int wave = tid >> 6;
    if ((tid & 63) == 0) { red[wave] = s; red[4 + wave] = s2; }
    __syncthreads();
    float S  = red[0] + red[1] + red[2] + red[3];
    float S2 = red[4] + red[5] + red[6] + red[7];
    float mean = S * (1.0f / 4096.0f);
    float var  = S2 * (1.0f / 4096.0f) - mean * mean;
    float rstd = rsqrtf(var + 1e-5f);
    float slope = prelu[(blk >> 5) & 3];
    float t;
    float4 o;
#define NRM(vv)                                                               \
    t = (vv.x - mean) * rstd; o.x = t >= 0.f ? t : slope * t;                 \
    t = (vv.y - mean) * rstd; o.y = t >= 0.f ? t : slope * t;                 \
    t = (vv.z - mean) * rstd; o.z = t >= 0.f ? t : slope * t;                 \
    t = (vv.w - mean) * rstd; o.w = t >= 0.f ? t : slope * t;
    NRM(v0); yp[tid]       = o;
    NRM(v1); yp[tid + 256] = o;
    NRM(v2); yp[tid + 512] = o;
    NRM(v3); yp[tid + 768] = o;
#undef NRM
}

extern "C" void kernel_launch(void* const* d_in, const int* in_sizes, int n_in,
                              void* d_out, int out_size, void* d_ws, size_t ws_size,
                              hipStream_t stream) {
    const float* x     = (const float*)d_in[0];
    const float* lw    = (const float*)d_in[1];
    const float* prelu = (const float*)d_in[2];
    float*  out = (float*)d_out;
    ushort* w2  = (ushort*)d_ws;                        // 5184*16 = 82,944 B

    wtrans<<<21, 256, 0, stream>>>(lw, w2);
    dim3 grid(64, 8, 4);
    kanconv<<<grid, 256, 0, stream>>>(x, w2, out);
    instnorm<<<1024, 256, 0, stream>>>(out, prelu);
}

// Round 7
// 40.777 us; speedup vs baseline: 1.3768x; 1.0468x over previous
//
#include <hip/hip_runtime.h>
#include <hip/hip_bf16.h>
#include <math.h>

typedef __attribute__((ext_vector_type(8))) short short8;
typedef __attribute__((ext_vector_type(4))) float f32x4;
typedef __attribute__((ext_vector_type(16))) float f32x16;
typedef unsigned int u32;
typedef unsigned long long u64;

// ---------------------------------------------------------------------------
// Weight pack: layer_weight (32,144,3,3) f32 -> bf16 A-fragments for
// mfma_f32_32x32x16_bf16 (weights = A operand, M=32=oc, K=144).
// Page = tap*9 + ks (81 pages x 64 lanes x 8 bf16).
// A-frag: row(oc) = lane&31, k = ks*16 + (lane>>5)*8 + e.
// k-order: k<128 -> spline (icg*8+jj) [= lw channel order], 128..143 -> gelu.
// ---------------------------------------------------------------------------
__global__ void wtrans(const float* __restrict__ lw, ushort* __restrict__ w2) {
    int t = blockIdx.x * 256 + threadIdx.x;
    if (t >= 5184) return;
    int l    = t & 63;
    int page = t >> 6;          // 0..80
    int ks  = page % 9;
    int tap = page / 9;
    int oc = l & 31;
    int kbase = ks * 16 + ((l >> 5) << 3);
    short8 v;
#pragma unroll
    for (int e = 0; e < 8; ++e) {
        int k = kbase + e;      // < 144 always
        float val = lw[(oc * 144 + k) * 9 + tap];
        __hip_bfloat16 hb = __float2bfloat16(val);
        v[e] = *(short*)&hb;
    }
    ((short8*)w2)[t] = v;
}

// ---------------------------------------------------------------------------
// MFMA implicit-GEMM KAN conv, 32x32x16 bf16, K=144.
// Block = (b, g, 4x16 tile). Halo 6x18 = 108 px, row stride 152 ushort.
// Waves partition TAPS ({0,1},{2,3},{4,5},{6,7,8}) so every weight fragment
// is fetched once per block (81 KB); each wave computes BOTH pixel tiles.
// 4-way partial combine through LDS; waves 0/1 finalize tile 0/1.
// ---------------------------------------------------------------------------
__global__ __launch_bounds__(256, 4) void kanconv(const float* __restrict__ x,
                                                  const ushort* __restrict__ w2,
                                                  float* __restrict__ y) {
    __shared__ __align__(16) ushort Fs[108 * 152];   // 32,832 B
    const int tid  = threadIdx.x;
    const int tile = blockIdx.x;          // 0..63 : 16 row-tiles x 4 col-tiles
    const int b    = blockIdx.y;
    const int g    = blockIdx.z;
    const int h0 = (tile >> 2) * 4;
    const int w0 = (tile & 3) * 16;
    const float* xg = x + ((size_t)(b * 64 + g * 16)) * 4096;

    // ---- phase 1: prefetch the 7 x values (independent loads, overlapped) --
    float xv[7];
    unsigned imgbits = 0;
#pragma unroll
    for (int it = 0; it < 7; ++it) {
        int e = it * 256 + tid;
        float v = 0.f;
        if (e < 1728) {
            int icg = e / 108;
            int p   = e - icg * 108;
            int py = p / 18, px = p - py * 18;
            int hy = h0 + py - 1, wx = w0 + px - 1;
            if (((unsigned)hy < 64u) && ((unsigned)wx < 64u)) {
                v = xg[icg * 4096 + hy * 64 + wx];
                imgbits |= (1u << it);
            }
        }
        xv[it] = v;
    }

    // ---- phase 2: feature math + LDS writes ----
#pragma unroll
    for (int it = 0; it < 7; ++it) {
        int e = it * 256 + tid;
        if (e < 1728) {
            int icg = e / 108;
            int p   = e - icg * 108;
            bool img = (imgbits >> it) & 1u;
            float v = xv[it];
            // uniform cubic B-spline closed form; knots -2.2 + 0.4*i
            float tpos = (v + 2.2f) * 2.5f;
            float cf = floorf(tpos);
            int ci = (int)cf;
            float u = tpos - cf;
            float u2 = u * u, u3 = u2 * u, om = 1.f - u;
            const float s6 = 1.f / 6.f;
            float q0 = om * om * om * s6;
            float q1 = (4.f - 6.f * u2 + 3.f * u3) * s6;
            float q2 = (1.f + 3.f * u + 3.f * u2 - 3.f * u3) * s6;
            float q3 = u3 * s6;
            __hip_bfloat16 hq0 = __float2bfloat16(q0);
            __hip_bfloat16 hq1 = __float2bfloat16(q1);
            __hip_bfloat16 hq2 = __float2bfloat16(q2);
            __hip_bfloat16 hq3 = __float2bfloat16(q3);
            u64 Q =   (u64)*(ushort*)&hq0
                    | ((u64)*(ushort*)&hq1 << 16)
                    | ((u64)*(ushort*)&hq2 << 32)
                    | ((u64)*(ushort*)&hq3 << 48);
            u64 lo = 0, hi = 0;
            if (img && ci >= 0 && ci <= 10) {
                int s = ci * 16 - 48;
                if (s < 0)        { lo = Q >> (-s); }
                else if (s < 64)  { lo = Q << s; hi = s ? (Q >> (64 - s)) : 0ull; }
                else              { hi = Q << (s - 64); }
            }
            union { u64 u64v[2]; short8 s8; } un;
            un.u64v[0] = lo; un.u64v[1] = hi;
            ushort* row = &Fs[p * 152];
            *(short8*)(row + icg * 8) = un.s8;
            // gelu via branch-free poly erf (A&S 7.1.26); v==0 -> ge==0 (pad ok)
            float z  = v * 0.70710678118654752f;
            float az = fabsf(z);
            float tt = 1.f / fmaf(0.3275911f, az, 1.f);
            float poly = tt * fmaf(tt, fmaf(tt, fmaf(tt, fmaf(tt, 1.061405429f,
                          -1.453152027f), 1.421413741f), -0.284496736f),
                          0.254829592f);
            float er = 1.f - poly * __expf(-z * z);
            er = (z < 0.f) ? -er : er;
            float ge = 0.5f * v * (1.f + er);
            __hip_bfloat16 hg = __float2bfloat16(ge);
            row[128 + icg] = *(ushort*)&hg;
        }
    }
    __syncthreads();

    const int wv = tid >> 6;
    const int l  = tid & 63;
    const int la = l & 31, klo = l >> 5;
    const int p0row = la >> 4, p0col = la & 15;   // tile0: rows 0-1; tile1: +2

    f32x16 accA, accB;
#pragma unroll
    for (int i = 0; i < 16; ++i) { accA[i] = 0.f; accB[i] = 0.f; }
    const short8* w8 = (const short8*)w2;
    const int tap_lo = wv * 2;
    const int tap_hi = (wv == 3) ? 9 : wv * 2 + 2;

#pragma unroll 1
    for (int tap = tap_lo; tap < tap_hi; ++tap) {
        const int kh = tap / 3, kw = tap - kh * 3;
        const ushort* fb0 = &Fs[((p0row + kh) * 18 + (p0col + kw)) * 152 + klo * 8];
        const ushort* fb1 = fb0 + 2 * 18 * 152;
        const short8* ap = w8 + tap * 576 + l;
#pragma unroll
        for (int ks = 0; ks < 9; ++ks) {
            short8 a   = ap[ks * 64];                        // weights (A), 1 wave only
            short8 bf0 = *(const short8*)(fb0 + ks * 16);    // tile0 features
            short8 bf1 = *(const short8*)(fb1 + ks * 16);    // tile1 features
            accA = __builtin_amdgcn_mfma_f32_32x32x16_bf16(a, bf0, accA, 0, 0, 0);
            accB = __builtin_amdgcn_mfma_f32_32x32x16_bf16(a, bf1, accB, 0, 0, 0);
        }
    }

    // ---- 4-way combine through LDS (reuse Fs; slot stride 16 dw, 2-way ok) --
    __syncthreads();                      // all feature reads done
    float* comb = (float*)Fs;             // [w*2+pt][lane][16] f32 = 32768 B
    if (wv != 0) {                        // tile0 partials from waves 1..3
        float* cp = comb + ((wv * 2 + 0) * 64 + l) * 16;
        *(f32x4*)(cp + 0)  = f32x4{accA[0], accA[1], accA[2], accA[3]};
        *(f32x4*)(cp + 4)  = f32x4{accA[4], accA[5], accA[6], accA[7]};
        *(f32x4*)(cp + 8)  = f32x4{accA[8], accA[9], accA[10], accA[11]};
        *(f32x4*)(cp + 12) = f32x4{accA[12], accA[13], accA[14], accA[15]};
    }
    if (wv != 1) {                        // tile1 partials from waves 0,2,3
        float* cp = comb + ((wv * 2 + 1) * 64 + l) * 16;
        *(f32x4*)(cp + 0)  = f32x4{accB[0], accB[1], accB[2], accB[3]};
        *(f32x4*)(cp + 4)  = f32x4{accB[4], accB[5], accB[6], accB[7]};
        *(f32x4*)(cp + 8)  = f32x4{accB[8], accB[9], accB[10], accB[11]};
        *(f32x4*)(cp + 12) = f32x4{accB[12], accB[13], accB[14], accB[15]};
    }
    __syncthreads();
    if (wv < 2) {
        f32x16 sum = (wv == 0) ? accA : accB;
#pragma unroll
        for (int w = 0; w < 4; ++w) {
            if (w == wv) continue;
            const float* cp = comb + ((w * 2 + wv) * 64 + l) * 16;
            f32x4 c0 = *(const f32x4*)(cp + 0);
            f32x4 c1 = *(const f32x4*)(cp + 4);
            f32x4 c2 = *(const f32x4*)(cp + 8);
            f32x4 c3 = *(const f32x4*)(cp + 12);
#pragma unroll
            for (int r = 0; r < 4; ++r) {
                sum[r]      += c0[r];
                sum[r + 4]  += c1[r];
                sum[r + 8]  += c2[r];
                sum[r + 12] += c3[r];
            }
        }
        // D: col(pixel) = lane&31, row(oc) = (r&3) + 8*(r>>2) + 4*klo
        const int pix = wv * 32 + la;
        const int prow = pix >> 4, pcol = pix & 15;
        float* yb = y + (((size_t)b * 128 + g * 32) * 64 + h0 + prow) * 64
                      + w0 + pcol;
#pragma unroll
        for (int r = 0; r < 16; ++r) {
            int oc = (r & 3) + 8 * (r >> 2) + 4 * klo;
            yb[(size_t)oc * 4096] = sum[r];
        }
    }
}

// ---------------------------------------------------------------------------
// Fused instance-norm + PReLU: one block per (b,c); 16 floats/thread in regs.
// ---------------------------------------------------------------------------
__global__ __launch_bounds__(256) void instnorm(float* __restrict__ y,
                                                const float* __restrict__ prelu) {
    const int blk = blockIdx.x;  // b*128 + c
    const int tid = threadIdx.x;
    float4* yp = (float4*)(y + (size_t)blk * 4096);
    float4 v0 = yp[tid], v1 = yp[tid + 256], v2 = yp[tid + 512], v3 = yp[tid + 768];
    float s  = v0.x + v0.y + v0.z + v0.w + v1.x + v1.y + v1.z + v1.w
             + v2.x + v2.y + v2.z + v2.w + v3.x + v3.y + v3.z + v3.w;
    float s2 = v0.x*v0.x + v0.y*v0.y + v0.z*v0.z + v0.w*v0.w
             + v1.x*v1.x + v1.y*v1.y + v1.z*v1.z + v1.w*v1.w
             + v2.x*v2.x + v2.y*v2.y + v2.z*v2.z + v2.w*v2.w
             + v3.x*v3.x + v3.y*v3.y + v3.z*v3.z + v3.w*v3.w;
#pragma unroll
    for (int off = 32; off > 0; off >>= 1) {
        s  += __shfl_down(s, off);
        s2 += __shfl_down(s2, off);
    }
    __shared__ float red[8];
    int wave = tid >> 6;
    if ((tid & 63) == 0) { red[wave] = s; red[4 + wave] = s2; }
    __syncthreads();
    float S  = red[0] + red[1] + red[2] + red[3];
    float S2 = red[4] + red[5] + red[6] + red[7];
    float mean = S * (1.0f / 4096.0f);
    float var  = S2 * (1.0f / 4096.0f) - mean * mean;
    float rstd = rsqrtf(var + 1e-5f);
    float slope = prelu[(blk >> 5) & 3];
    float t;
    float4 o;
#define NRM(vv)                                                               \
    t = (vv.x - mean) * rstd; o.x = t >= 0.f ? t : slope * t;                 \
    t = (vv.y - mean) * rstd; o.y = t >= 0.f ? t : slope * t;                 \
    t = (vv.z - mean) * rstd; o.z = t >= 0.f ? t : slope * t;                 \
    t = (vv.w - mean) * rstd; o.w = t >= 0.f ? t : slope * t;
    NRM(v0); yp[tid]       = o;
    NRM(v1); yp[tid + 256] = o;
    NRM(v2); yp[tid + 512] = o;
    NRM(v3); yp[tid + 768] = o;
#undef NRM
}

extern "C" void kernel_launch(void* const* d_in, const int* in_sizes, int n_in,
                              void* d_out, int out_size, void* d_ws, size_t ws_size,
                              hipStream_t stream) {
    const float* x     = (const float*)d_in[0];
    const float* lw    = (const float*)d_in[1];
    const float* prelu = (const float*)d_in[2];
    float*  out = (float*)d_out;
    ushort* w2  = (ushort*)d_ws;                        // 5184*16 = 82,944 B

    wtrans<<<21, 256, 0, stream>>>(lw, w2);
    dim3 grid(64, 8, 4);
    kanconv<<<grid, 256, 0, stream>>>(x, w2, out);
    instnorm<<<1024, 256, 0, stream>>>(out, prelu);
}

// Round 8
// 40.670 us; speedup vs baseline: 1.3804x; 1.0026x over previous
//
#include <hip/hip_runtime.h>
#include <hip/hip_bf16.h>
#include <math.h>

typedef __attribute__((ext_vector_type(8))) short short8;
typedef __attribute__((ext_vector_type(4))) float f32x4;
typedef __attribute__((ext_vector_type(16))) float f32x16;
typedef unsigned int u32;
typedef unsigned long long u64;

// fast round-to-nearest-even f32 -> bf16 (values are finite; no NaN path)
__device__ __forceinline__ ushort f2bf(float f) {
    u32 u = __float_as_uint(f);
    return (ushort)((u + 0x7fffu + ((u >> 16) & 1u)) >> 16);
}

// ---------------------------------------------------------------------------
// Weight pack: layer_weight (32,144,3,3) f32 -> bf16 A-fragments for
// mfma_f32_32x32x16_bf16 (weights = A operand, M=32=oc, K=144).
// Page = tap*9 + ks (81 pages x 64 lanes x 8 bf16).
// A-frag: row(oc) = lane&31, k = ks*16 + (lane>>5)*8 + e.
// ---------------------------------------------------------------------------
__global__ void wtrans(const float* __restrict__ lw, ushort* __restrict__ w2) {
    int t = blockIdx.x * 256 + threadIdx.x;
    if (t >= 5184) return;
    int l    = t & 63;
    int page = t >> 6;          // 0..80
    int ks  = page % 9;
    int tap = page / 9;
    int oc = l & 31;
    int kbase = ks * 16 + ((l >> 5) << 3);
    short8 v;
#pragma unroll
    for (int e = 0; e < 8; ++e) {
        int k = kbase + e;      // < 144 always
        v[e] = (short)f2bf(lw[(oc * 144 + k) * 9 + tap]);
    }
    ((short8*)w2)[t] = v;
}

// ---------------------------------------------------------------------------
// MFMA implicit-GEMM KAN conv, 32x32x16 bf16, K=144. Output = RAW bf16 y
// (un-normalized) to workspace. Block = (b, g, 4x16 tile), halo 6x18,
// row stride 152 ushort. Waves partition TAPS ({0,1},{2,3},{4,5},{6,7,8});
// each wave computes both pixel tiles; 4-way combine via LDS.
// ---------------------------------------------------------------------------
__global__ __launch_bounds__(256, 4) void kanconv(const float* __restrict__ x,
                                                  const ushort* __restrict__ w2,
                                                  ushort* __restrict__ yraw) {
    __shared__ __align__(16) ushort Fs[108 * 152];   // 32,832 B
    const int tid  = threadIdx.x;
    const int tile = blockIdx.x;          // 0..63 : 16 row-tiles x 4 col-tiles
    const int b    = blockIdx.y;
    const int g    = blockIdx.z;
    const int h0 = (tile >> 2) * 4;
    const int w0 = (tile & 3) * 16;
    const float* xg = x + ((size_t)(b * 64 + g * 16)) * 4096;

    // ---- phase 1: prefetch the 7 x values (independent loads, overlapped) --
    float xv[7];
    unsigned imgbits = 0;
#pragma unroll
    for (int it = 0; it < 7; ++it) {
        int e = it * 256 + tid;
        float v = 0.f;
        if (e < 1728) {
            int icg = e / 108;
            int p   = e - icg * 108;
            int py = p / 18, px = p - py * 18;
            int hy = h0 + py - 1, wx = w0 + px - 1;
            if (((unsigned)hy < 64u) && ((unsigned)wx < 64u)) {
                v = xg[icg * 4096 + hy * 64 + wx];
                imgbits |= (1u << it);
            }
        }
        xv[it] = v;
    }

    // ---- phase 2: feature math + LDS writes ----
#pragma unroll
    for (int it = 0; it < 7; ++it) {
        int e = it * 256 + tid;
        if (e < 1728) {
            int icg = e / 108;
            int p   = e - icg * 108;
            bool img = (imgbits >> it) & 1u;
            float v = xv[it];
            // uniform cubic B-spline closed form; knots -2.2 + 0.4*i
            float tpos = (v + 2.2f) * 2.5f;
            float cf = floorf(tpos);
            int ci = (int)cf;
            float u = tpos - cf;
            float u2 = u * u, u3 = u2 * u, om = 1.f - u;
            const float s6 = 1.f / 6.f;
            float q0 = om * om * om * s6;
            float q1 = (4.f - 6.f * u2 + 3.f * u3) * s6;
            float q2 = (1.f + 3.f * u + 3.f * u2 - 3.f * u3) * s6;
            float q3 = u3 * s6;
            u64 Q =   (u64)f2bf(q0)
                    | ((u64)f2bf(q1) << 16)
                    | ((u64)f2bf(q2) << 32)
                    | ((u64)f2bf(q3) << 48);
            u64 lo = 0, hi = 0;
            if (img && ci >= 0 && ci <= 10) {
                int s = ci * 16 - 48;
                if (s < 0)        { lo = Q >> (-s); }
                else if (s < 64)  { lo = Q << s; hi = s ? (Q >> (64 - s)) : 0ull; }
                else              { hi = Q << (s - 64); }
            }
            union { u64 u64v[2]; short8 s8; } un;
            un.u64v[0] = lo; un.u64v[1] = hi;
            ushort* row = &Fs[p * 152];
            *(short8*)(row + icg * 8) = un.s8;
            // gelu via branch-free poly erf (A&S 7.1.26); v==0 -> ge==0
            float z  = v * 0.70710678118654752f;
            float az = fabsf(z);
            float tt = 1.f / fmaf(0.3275911f, az, 1.f);
            float poly = tt * fmaf(tt, fmaf(tt, fmaf(tt, fmaf(tt, 1.061405429f,
                          -1.453152027f), 1.421413741f), -0.284496736f),
                          0.254829592f);
            float er = 1.f - poly * __expf(-z * z);
            er = (z < 0.f) ? -er : er;
            float ge = 0.5f * v * (1.f + er);
            row[128 + icg] = f2bf(ge);
        }
    }
    __syncthreads();

    const int wv = tid >> 6;
    const int l  = tid & 63;
    const int la = l & 31, klo = l >> 5;
    const int p0row = la >> 4, p0col = la & 15;   // tile0: rows 0-1; tile1: +2

    f32x16 accA, accB;
#pragma unroll
    for (int i = 0; i < 16; ++i) { accA[i] = 0.f; accB[i] = 0.f; }
    const short8* w8 = (const short8*)w2;
    const int tap_lo = wv * 2;
    const int tap_hi = (wv == 3) ? 9 : wv * 2 + 2;

#pragma unroll 1
    for (int tap = tap_lo; tap < tap_hi; ++tap) {
        const int kh = tap / 3, kw = tap - kh * 3;
        const ushort* fb0 = &Fs[((p0row + kh) * 18 + (p0col + kw)) * 152 + klo * 8];
        const ushort* fb1 = fb0 + 2 * 18 * 152;
        const short8* ap = w8 + tap * 576 + l;
#pragma unroll
        for (int ks = 0; ks < 9; ++ks) {
            short8 a   = ap[ks * 64];                        // weights (A)
            short8 bf0 = *(const short8*)(fb0 + ks * 16);    // tile0 features
            short8 bf1 = *(const short8*)(fb1 + ks * 16);    // tile1 features
            accA = __builtin_amdgcn_mfma_f32_32x32x16_bf16(a, bf0, accA, 0, 0, 0);
            accB = __builtin_amdgcn_mfma_f32_32x32x16_bf16(a, bf1, accB, 0, 0, 0);
        }
    }

    // ---- 4-way combine through LDS ----
    __syncthreads();                      // all feature reads done
    float* comb = (float*)Fs;             // [w*2+pt][lane][16] f32 = 32768 B
    if (wv != 0) {                        // tile0 partials from waves 1..3
        float* cp = comb + ((wv * 2 + 0) * 64 + l) * 16;
        *(f32x4*)(cp + 0)  = f32x4{accA[0], accA[1], accA[2], accA[3]};
        *(f32x4*)(cp + 4)  = f32x4{accA[4], accA[5], accA[6], accA[7]};
        *(f32x4*)(cp + 8)  = f32x4{accA[8], accA[9], accA[10], accA[11]};
        *(f32x4*)(cp + 12) = f32x4{accA[12], accA[13], accA[14], accA[15]};
    }
    if (wv != 1) {                        // tile1 partials from waves 0,2,3
        float* cp = comb + ((wv * 2 + 1) * 64 + l) * 16;
        *(f32x4*)(cp + 0)  = f32x4{accB[0], accB[1], accB[2], accB[3]};
        *(f32x4*)(cp + 4)  = f32x4{accB[4], accB[5], accB[6], accB[7]};
        *(f32x4*)(cp + 8)  = f32x4{accB[8], accB[9], accB[10], accB[11]};
        *(f32x4*)(cp + 12) = f32x4{accB[12], accB[13], accB[14], accB[15]};
    }
    __syncthreads();
    if (wv < 2) {
        f32x16 sum = (wv == 0) ? accA : accB;
#pragma unroll
        for (int w = 0; w < 4; ++w) {
            if (w == wv) continue;
            const float* cp = comb + ((w * 2 + wv) * 64 + l) * 16;
            f32x4 c0 = *(const f32x4*)(cp + 0);
            f32x4 c1 = *(const f32x4*)(cp + 4);
            f32x4 c2 = *(const f32x4*)(cp + 8);
            f32x4 c3 = *(const f32x4*)(cp + 12);
#pragma unroll
            for (int r = 0; r < 4; ++r) {
                sum[r]      += c0[r];
                sum[r + 4]  += c1[r];
                sum[r + 8]  += c2[r];
                sum[r + 12] += c3[r];
            }
        }
        // D: col(pixel) = lane&31, row(oc) = (r&3) + 8*(r>>2) + 4*klo
        const int pix = wv * 32 + la;
        const int prow = pix >> 4, pcol = pix & 15;
        ushort* yb = yraw + (((size_t)b * 128 + g * 32) * 64 + h0 + prow) * 64
                          + w0 + pcol;
#pragma unroll
        for (int r = 0; r < 16; ++r) {
            int oc = (r & 3) + 8 * (r >> 2) + 4 * klo;
            yb[(size_t)oc * 4096] = f2bf(sum[r]);
        }
    }
}

// ---------------------------------------------------------------------------
// Instance-norm + PReLU from bf16 raw y: one block per (b,c); 16 vals/thread
// in registers; read 8 KB bf16, write 16 KB f32.
// ---------------------------------------------------------------------------
__global__ __launch_bounds__(256) void instnorm(const ushort* __restrict__ yraw,
                                                float* __restrict__ y,
                                                const float* __restrict__ prelu) {
    const int blk = blockIdx.x;  // b*128 + c
    const int tid = threadIdx.x;
    const short8* rp = (const short8*)(yraw + (size_t)blk * 4096);
    short8 a = rp[tid], c = rp[tid + 256];
    float v[16];
#pragma unroll
    for (int j = 0; j < 8; ++j) {
        v[j]     = __uint_as_float(((u32)(ushort)a[j]) << 16);
        v[8 + j] = __uint_as_float(((u32)(ushort)c[j]) << 16);
    }
    float s = 0.f, s2 = 0.f;
#pragma unroll
    for (int j = 0; j < 16; ++j) { s += v[j]; s2 += v[j] * v[j]; }
#pragma unroll
    for (int off = 32; off > 0; off >>= 1) {
        s  += __shfl_down(s, off);
        s2 += __shfl_down(s2, off);
    }
    __shared__ float red[8];
    int wave = tid >> 6;
    if ((tid & 63) == 0) { red[wave] = s; red[4 + wave] = s2; }
    __syncthreads();
    float S  = red[0] + red[1] + red[2] + red[3];
    float S2 = red[4] + red[5] + red[6] + red[7];
    float mean = S * (1.0f / 4096.0f);
    float var  = S2 * (1.0f / 4096.0f) - mean * mean;
    float rstd = rsqrtf(var + 1e-5f);
    float slope = prelu[(blk >> 5) & 3];
    float* yp = y + (size_t)blk * 4096;
#pragma unroll
    for (int j = 0; j < 16; ++j) {
        int idx = (j < 8) ? (tid * 8 + j) : (2048 + tid * 8 + (j - 8));
        float t = (v[j] - mean) * rstd;
        yp[idx] = t >= 0.f ? t : slope * t;
    }
}

extern "C" void kernel_launch(void* const* d_in, const int* in_sizes, int n_in,
                              void* d_out, int out_size, void* d_ws, size_t ws_size,
                              hipStream_t stream) {
    const float* x     = (const float*)d_in[0];
    const float* lw    = (const float*)d_in[1];
    const float* prelu = (const float*)d_in[2];
    float*  out  = (float*)d_out;
    ushort* w2   = (ushort*)d_ws;                       // 82,944 B
    ushort* yraw = (ushort*)((char*)d_ws + 92160);      // 8 MB bf16 raw y

    wtrans<<<21, 256, 0, stream>>>(lw, w2);
    dim3 grid(64, 8, 4);
    kanconv<<<grid, 256, 0, stream>>>(x, w2, yraw);
    instnorm<<<1024, 256, 0, stream>>>(yraw, out, prelu);
}